// Round 4
// baseline (459.092 us; speedup 1.0000x reference)
//
#include <hip/hip_runtime.h>
#include <hip/hip_bf16.h>

// GAT attention head, N=8192, F_IN=256, OUT=64, bias_mat [N,N] f32.
// kA: fts = seq@W1 (bf16 MFMA), f1/f2 rank-1 terms, ftsT bf16 for PV B-frags.
// kB v4: v1 skeleton (cooperative LDS bias staging = 1 DRAM stream per row),
//   but 2KB-per-row bursts (16 rounds, 32 barriers), 1-round reg prefetch of
//   bias, ping-pong reg prefetch of L2-resident fts/f2 (no LDS staging for
//   them). LDS geometry tuned to the wave64 b128 conflict-free minimum.
//   Numerics identical to round-1-verified code (P in A-frag layout, T13).

typedef float f32x4 __attribute__((ext_vector_type(4)));
typedef short bf16x8 __attribute__((ext_vector_type(8)));

__device__ __forceinline__ unsigned short f2bf(float x) {
    union { float f; unsigned u; } v; v.f = x;
    unsigned r = v.u + 0x7FFF + ((v.u >> 16) & 1);   // RNE
    return (unsigned short)(r >> 16);
}

__device__ __forceinline__ float elu1(float x) {
    return x > 0.f ? x : (__expf(x) - 1.f);
}

// ---------------- kernel A: fts, f1, f2, ftsT ----------------
// grid 256, block 256 (4 waves). Block handles 32 q-rows. (round-1 verified)
__global__ __launch_bounds__(256) void attn_fts(
    const float* __restrict__ seq, const float* __restrict__ W1,
    const float* __restrict__ a1, const float* __restrict__ b1,
    const float* __restrict__ a2, const float* __restrict__ b2,
    unsigned short* __restrict__ ftsT, float* __restrict__ f1g,
    float* __restrict__ f2g)
{
    __shared__ unsigned short w1t[64 * 264];      // W1^T bf16, 528B rows
    __shared__ unsigned short stage[64 * 40];     // ftsT staging [64 o][32 q +8]
    __shared__ float f1p[2][32];
    __shared__ float f2p[2][32];

    const int tid = threadIdx.x;
    const int qb = blockIdx.x * 32;
    const int w = tid >> 6, rg = w & 1, oh = w >> 1;
    const int lane = tid & 63, c = lane & 15, g = lane >> 4;

    for (int i = 0; i < 64; ++i) {
        int e = tid + i * 256;            // e = k*64 + o
        int k = e >> 6, o = e & 63;
        w1t[o * 264 + k] = f2bf(W1[e]);
    }
    __syncthreads();

    f32x4 acc[2] = {};
    const float* srow = seq + (long)(qb + rg * 16 + c) * 256;
    #pragma unroll
    for (int ks = 0; ks < 8; ++ks) {
        int k0 = ks * 32 + g * 8;
        float4 s0 = *(const float4*)(srow + k0);
        float4 s1 = *(const float4*)(srow + k0 + 4);
        bf16x8 af;
        af[0] = (short)f2bf(s0.x); af[1] = (short)f2bf(s0.y);
        af[2] = (short)f2bf(s0.z); af[3] = (short)f2bf(s0.w);
        af[4] = (short)f2bf(s1.x); af[5] = (short)f2bf(s1.y);
        af[6] = (short)f2bf(s1.z); af[7] = (short)f2bf(s1.w);
        #pragma unroll
        for (int ob = 0; ob < 2; ++ob) {
            int brow = oh * 32 + ob * 16 + c;
            bf16x8 bf = *(const bf16x8*)(&w1t[brow * 264 + k0]);
            acc[ob] = __builtin_amdgcn_mfma_f32_16x16x32_bf16(af, bf, acc[ob], 0, 0, 0);
        }
    }

    float a1v0 = a1[oh * 32 + c], a1v1 = a1[oh * 32 + 16 + c];
    float a2v0 = a2[oh * 32 + c], a2v1 = a2[oh * 32 + 16 + c];
    #pragma unroll
    for (int reg = 0; reg < 4; ++reg) {
        float p1 = acc[0][reg] * a1v0 + acc[1][reg] * a1v1;
        float p2 = acc[0][reg] * a2v0 + acc[1][reg] * a2v1;
        #pragma unroll
        for (int mm = 1; mm < 16; mm <<= 1) {
            p1 += __shfl_xor(p1, mm, 64);
            p2 += __shfl_xor(p2, mm, 64);
        }
        if (c == 0) {
            f1p[oh][rg * 16 + g * 4 + reg] = p1;
            f2p[oh][rg * 16 + g * 4 + reg] = p2;
        }
    }

    #pragma unroll
    for (int ob = 0; ob < 2; ++ob) {
        int row = oh * 32 + ob * 16 + c;
        #pragma unroll
        for (int rp = 0; rp < 2; ++rp) {
            unsigned short lo = f2bf(acc[ob][rp * 2]);
            unsigned short hi = f2bf(acc[ob][rp * 2 + 1]);
            unsigned v = (unsigned)lo | ((unsigned)hi << 16);
            *(unsigned*)(&stage[row * 40 + rg * 16 + g * 4 + rp * 2]) = v;
        }
    }
    __syncthreads();

    {
        int o = tid >> 2, q4 = tid & 3;
        uint4 v = *(const uint4*)(&stage[o * 40 + q4 * 8]);
        *(uint4*)(&ftsT[(long)o * 8192 + qb + q4 * 8]) = v;
    }
    if (tid < 32) {
        f1g[qb + tid] = f1p[0][tid] + f1p[1][tid] + b1[0];
        f2g[qb + tid] = f2p[0][tid] + f2p[1][tid] + b2[0];
    }
}

// ---------------- kernel B v4 ----------------
// grid 256, block 512 (8 waves). Block = 32 q-rows. Round = 512 j (2KB/row),
// 16 rounds. Wave (rg,h): rows rg*16+c, j-split h (128 j), 4 K-steps/round.
__global__ __launch_bounds__(512) void attn_main(
    const float* __restrict__ bias, const unsigned short* __restrict__ ftsT,
    const float* __restrict__ f1g, const float* __restrict__ f2g,
    float* __restrict__ out)
{
    __shared__ float blds[32][516];          // 66.0 KB; stride 516 ≡ 4 (mod 32) banks
    __shared__ float macc[2][4][16][68];     // 34.8 KB merge area
    __shared__ float mlm[2][4][16];
    __shared__ float mll[2][4][16];

    const int tid = threadIdx.x;
    const int qb = blockIdx.x * 32;
    const int w = tid >> 6, rg = w & 1, h = w >> 1;
    const int lane = tid & 63, c = lane & 15, g = lane >> 4;

    // staging roles: thread covers 4x 32B of one row (2KB row = 16 thr x 128B)
    const int srow = tid >> 4, schunk = tid & 15;
    const float* bias_base = bias + (long)(qb + srow) * 8192 + schunk * 8;

    const float f1r = f1g[qb + rg * 16 + c];
    const unsigned short* fts_base = ftsT + (long)c * 8192 + h * 128 + g * 8;
    const float* f2_base = f2g + h * 128 + g * 8;

    float4 pb[8];                            // bias prefetch: 4 k x 2 float4
    auto issue_bias = [&](int r) {
        const float* p = bias_base + r * 512;
        #pragma unroll
        for (int k = 0; k < 4; ++k) {
            pb[2 * k]     = ((const float4*)(p + k * 128))[0];
            pb[2 * k + 1] = ((const float4*)(p + k * 128))[1];
        }
    };

    bf16x8 fA[4], fB[4];
    float4 f2A0, f2A1, f2B0, f2B1;
    auto issue_ftsA = [&](int r, int ks) {
        const unsigned short* p = fts_base + r * 512 + ks * 32;
        fA[0] = *(const bf16x8*)(p);
        fA[1] = *(const bf16x8*)(p + 16 * 8192);
        fA[2] = *(const bf16x8*)(p + 32 * 8192);
        fA[3] = *(const bf16x8*)(p + 48 * 8192);
        const float* q = f2_base + r * 512 + ks * 32;
        f2A0 = ((const float4*)q)[0]; f2A1 = ((const float4*)q)[1];
    };
    auto issue_ftsB = [&](int r, int ks) {
        const unsigned short* p = fts_base + r * 512 + ks * 32;
        fB[0] = *(const bf16x8*)(p);
        fB[1] = *(const bf16x8*)(p + 16 * 8192);
        fB[2] = *(const bf16x8*)(p + 32 * 8192);
        fB[3] = *(const bf16x8*)(p + 48 * 8192);
        const float* q = f2_base + r * 512 + ks * 32;
        f2B0 = ((const float4*)q)[0]; f2B1 = ((const float4*)q)[1];
    };

    float m = -INFINITY, lsum = 0.f;
    f32x4 acc[4] = {};

    auto do_ks = [&](int jcol, const bf16x8 (&ff)[4],
                     const float4& fa, const float4& fb) {
        const float* bl = &blds[rg * 16 + c][jcol];
        float4 b0 = *(const float4*)(bl);
        float4 b1v = *(const float4*)(bl + 4);
        float bb[8] = { b0.x, b0.y, b0.z, b0.w, b1v.x, b1v.y, b1v.z, b1v.w };
        float f2v[8] = { fa.x, fa.y, fa.z, fa.w, fb.x, fb.y, fb.z, fb.w };
        float s[8];
        float tm = -INFINITY;
        #pragma unroll
        for (int i = 0; i < 8; ++i) {
            float z = f1r + f2v[i];
            z = fmaxf(z, 0.2f * z);               // leaky_relu(0.2)
            float sv = z + bb[i];
            s[i] = sv;
            tm = fmaxf(tm, sv);
        }
        tm = fmaxf(tm, __shfl_xor(tm, 16, 64));
        tm = fmaxf(tm, __shfl_xor(tm, 32, 64));
        if (!__all(tm <= m + 8.f)) {              // defer-max (T13)
            float mnew = fmaxf(m, tm);
            float sc = __expf(m - mnew);
            lsum *= sc;
            float scq[4];
            #pragma unroll
            for (int reg = 0; reg < 4; ++reg) scq[reg] = __shfl(sc, g * 4 + reg, 64);
            #pragma unroll
            for (int ob = 0; ob < 4; ++ob)
                #pragma unroll
                for (int reg = 0; reg < 4; ++reg) acc[ob][reg] *= scq[reg];
            m = mnew;
        }
        float ts = 0.f;
        bf16x8 af;
        #pragma unroll
        for (int i = 0; i < 8; ++i) {
            float p = __expf(s[i] - m);           // bounded by e^8 when deferred
            ts += p;
            af[i] = (short)f2bf(p);
        }
        ts += __shfl_xor(ts, 16, 64);
        ts += __shfl_xor(ts, 32, 64);
        lsum += ts;
        acc[0] = __builtin_amdgcn_mfma_f32_16x16x32_bf16(af, ff[0], acc[0], 0, 0, 0);
        acc[1] = __builtin_amdgcn_mfma_f32_16x16x32_bf16(af, ff[1], acc[1], 0, 0, 0);
        acc[2] = __builtin_amdgcn_mfma_f32_16x16x32_bf16(af, ff[2], acc[2], 0, 0, 0);
        acc[3] = __builtin_amdgcn_mfma_f32_16x16x32_bf16(af, ff[3], acc[3], 0, 0, 0);
    };

    const int jc0 = h * 128 + g * 8;

    // prologue
    issue_bias(0);
    issue_ftsA(0, 0);

    #pragma unroll 1
    for (int r = 0; r < 16; ++r) {
        __syncthreads();                         // blds free
        #pragma unroll
        for (int k = 0; k < 4; ++k) {
            *(float4*)(&blds[srow][k * 128 + schunk * 8])     = pb[2 * k];
            *(float4*)(&blds[srow][k * 128 + schunk * 8 + 4]) = pb[2 * k + 1];
        }
        if (r < 15) issue_bias(r + 1);           // in flight across consume
        __syncthreads();                         // blds ready

        issue_ftsB(r, 1);
        do_ks(jc0,      fA, f2A0, f2A1);         // ks=0
        issue_ftsA(r, 2);
        do_ks(jc0 + 32, fB, f2B0, f2B1);         // ks=1
        issue_ftsB(r, 3);
        do_ks(jc0 + 64, fA, f2A0, f2A1);         // ks=2
        if (r < 15) issue_ftsA(r + 1, 0);
        do_ks(jc0 + 96, fB, f2B0, f2B1);         // ks=3
    }

    __syncthreads();
    #pragma unroll
    for (int ob = 0; ob < 4; ++ob)
        #pragma unroll
        for (int reg = 0; reg < 4; ++reg)
            macc[rg][h][g * 4 + reg][ob * 16 + c] = acc[ob][reg];
    if (lane < 16) { mlm[rg][h][c] = m; mll[rg][h][c] = lsum; }
    __syncthreads();

    // merge 4 j-splits, normalize, elu, store: 512 thr x 4 outputs
    {
        const int row = tid >> 4;            // 0..31
        const int o0 = (tid & 15) * 4;
        const int rg2 = row >> 4, rr = row & 15;
        float m0 = mlm[rg2][0][rr], m1 = mlm[rg2][1][rr];
        float m2 = mlm[rg2][2][rr], m3 = mlm[rg2][3][rr];
        float ms = fmaxf(fmaxf(m0, m1), fmaxf(m2, m3));
        float w0 = __expf(m0 - ms), w1 = __expf(m1 - ms);
        float w2 = __expf(m2 - ms), w3 = __expf(m3 - ms);
        float den = mll[rg2][0][rr] * w0 + mll[rg2][1][rr] * w1 +
                    mll[rg2][2][rr] * w2 + mll[rg2][3][rr] * w3;
        float inv = 1.f / den;
        float4 v0 = *(const float4*)(&macc[rg2][0][rr][o0]);
        float4 v1 = *(const float4*)(&macc[rg2][1][rr][o0]);
        float4 v2 = *(const float4*)(&macc[rg2][2][rr][o0]);
        float4 v3 = *(const float4*)(&macc[rg2][3][rr][o0]);
        float4 res;
        res.x = elu1((v0.x * w0 + v1.x * w1 + v2.x * w2 + v3.x * w3) * inv);
        res.y = elu1((v0.y * w0 + v1.y * w1 + v2.y * w2 + v3.y * w3) * inv);
        res.z = elu1((v0.z * w0 + v1.z * w1 + v2.z * w2 + v3.z * w3) * inv);
        res.w = elu1((v0.w * w0 + v1.w * w1 + v2.w * w2 + v3.w * w3) * inv);
        *(float4*)(&out[(long)(qb + row) * 64 + o0]) = res;
    }
}

extern "C" void kernel_launch(void* const* d_in, const int* in_sizes, int n_in,
                              void* d_out, int out_size, void* d_ws, size_t ws_size,
                              hipStream_t stream) {
    (void)in_sizes; (void)n_in; (void)out_size; (void)ws_size;
    const float* seq  = (const float*)d_in[0];
    const float* bias = (const float*)d_in[1];
    const float* W1   = (const float*)d_in[2];
    const float* a1   = (const float*)d_in[3];
    const float* b1   = (const float*)d_in[4];
    const float* a2   = (const float*)d_in[5];
    const float* b2   = (const float*)d_in[6];
    float* out = (float*)d_out;

    unsigned short* ftsT = (unsigned short*)d_ws;                      // 1 MB
    float* f1 = (float*)((char*)d_ws + 64 * 8192 * 2);                 // 32 KB
    float* f2 = (float*)((char*)d_ws + 64 * 8192 * 2 + 8192 * 4);      // 32 KB

    hipLaunchKernelGGL(attn_fts, dim3(256), dim3(256), 0, stream,
                       seq, W1, a1, b1, a2, b2, ftsT, f1, f2);
    hipLaunchKernelGGL(attn_main, dim3(256), dim3(512), 0, stream,
                       bias, ftsT, f1, f2, out);
}

// Round 5
// 395.817 us; speedup vs baseline: 1.1599x; 1.1599x over previous
//
#include <hip/hip_runtime.h>
#include <hip/hip_bf16.h>

// GAT attention head, N=8192, F_IN=256, OUT=64, bias_mat [N,N] f32.
// kA: fts = seq@W1 (bf16 MFMA), f1/f2 rank-1 terms, ftsT bf16 for PV B-frags.
// kB v5: bias staged via global_load_lds (no staging regs -> no spills),
//   single barrier per round (issue-after-barrier => drain covers loads issued
//   one full round earlier), double-buffered LDS, 512 blocks x 256 thr
//   (16 q-rows, 4-way j-split), 2 blocks/CU. fts/f2 direct-to-reg (L2-hot).
//   Numerics identical to round-1-verified code (P in A-frag layout, T13).

typedef float f32x4 __attribute__((ext_vector_type(4)));
typedef short bf16x8 __attribute__((ext_vector_type(8)));

__device__ __forceinline__ unsigned short f2bf(float x) {
    union { float f; unsigned u; } v; v.f = x;
    unsigned r = v.u + 0x7FFF + ((v.u >> 16) & 1);   // RNE
    return (unsigned short)(r >> 16);
}

__device__ __forceinline__ float elu1(float x) {
    return x > 0.f ? x : (__expf(x) - 1.f);
}

// async global -> LDS, 16B per lane (wave-uniform LDS base, per-lane gsrc)
__device__ __forceinline__ void gld_lds16(const void* g, void* l) {
    __builtin_amdgcn_global_load_lds(
        (const __attribute__((address_space(1))) void*)(unsigned long long)g,
        (__attribute__((address_space(3))) void*)(unsigned)(unsigned long long)l,
        16, 0, 0);
}

// ---------------- kernel A: fts, f1, f2, ftsT ----------------
// grid 256, block 256 (4 waves). Block handles 32 q-rows. (round-1 verified)
__global__ __launch_bounds__(256) void attn_fts(
    const float* __restrict__ seq, const float* __restrict__ W1,
    const float* __restrict__ a1, const float* __restrict__ b1,
    const float* __restrict__ a2, const float* __restrict__ b2,
    unsigned short* __restrict__ ftsT, float* __restrict__ f1g,
    float* __restrict__ f2g)
{
    __shared__ unsigned short w1t[64 * 264];      // W1^T bf16, 528B rows
    __shared__ unsigned short stage[64 * 40];     // ftsT staging [64 o][32 q +8]
    __shared__ float f1p[2][32];
    __shared__ float f2p[2][32];

    const int tid = threadIdx.x;
    const int qb = blockIdx.x * 32;
    const int w = tid >> 6, rg = w & 1, oh = w >> 1;
    const int lane = tid & 63, c = lane & 15, g = lane >> 4;

    for (int i = 0; i < 64; ++i) {
        int e = tid + i * 256;            // e = k*64 + o
        int k = e >> 6, o = e & 63;
        w1t[o * 264 + k] = f2bf(W1[e]);
    }
    __syncthreads();

    f32x4 acc[2] = {};
    const float* srow = seq + (long)(qb + rg * 16 + c) * 256;
    #pragma unroll
    for (int ks = 0; ks < 8; ++ks) {
        int k0 = ks * 32 + g * 8;
        float4 s0 = *(const float4*)(srow + k0);
        float4 s1 = *(const float4*)(srow + k0 + 4);
        bf16x8 af;
        af[0] = (short)f2bf(s0.x); af[1] = (short)f2bf(s0.y);
        af[2] = (short)f2bf(s0.z); af[3] = (short)f2bf(s0.w);
        af[4] = (short)f2bf(s1.x); af[5] = (short)f2bf(s1.y);
        af[6] = (short)f2bf(s1.z); af[7] = (short)f2bf(s1.w);
        #pragma unroll
        for (int ob = 0; ob < 2; ++ob) {
            int brow = oh * 32 + ob * 16 + c;
            bf16x8 bf = *(const bf16x8*)(&w1t[brow * 264 + k0]);
            acc[ob] = __builtin_amdgcn_mfma_f32_16x16x32_bf16(af, bf, acc[ob], 0, 0, 0);
        }
    }

    float a1v0 = a1[oh * 32 + c], a1v1 = a1[oh * 32 + 16 + c];
    float a2v0 = a2[oh * 32 + c], a2v1 = a2[oh * 32 + 16 + c];
    #pragma unroll
    for (int reg = 0; reg < 4; ++reg) {
        float p1 = acc[0][reg] * a1v0 + acc[1][reg] * a1v1;
        float p2 = acc[0][reg] * a2v0 + acc[1][reg] * a2v1;
        #pragma unroll
        for (int mm = 1; mm < 16; mm <<= 1) {
            p1 += __shfl_xor(p1, mm, 64);
            p2 += __shfl_xor(p2, mm, 64);
        }
        if (c == 0) {
            f1p[oh][rg * 16 + g * 4 + reg] = p1;
            f2p[oh][rg * 16 + g * 4 + reg] = p2;
        }
    }

    #pragma unroll
    for (int ob = 0; ob < 2; ++ob) {
        int row = oh * 32 + ob * 16 + c;
        #pragma unroll
        for (int rp = 0; rp < 2; ++rp) {
            unsigned short lo = f2bf(acc[ob][rp * 2]);
            unsigned short hi = f2bf(acc[ob][rp * 2 + 1]);
            unsigned v = (unsigned)lo | ((unsigned)hi << 16);
            *(unsigned*)(&stage[row * 40 + rg * 16 + g * 4 + rp * 2]) = v;
        }
    }
    __syncthreads();

    {
        int o = tid >> 2, q4 = tid & 3;
        uint4 v = *(const uint4*)(&stage[o * 40 + q4 * 8]);
        *(uint4*)(&ftsT[(long)o * 8192 + qb + q4 * 8]) = v;
    }
    if (tid < 32) {
        f1g[qb + tid] = f1p[0][tid] + f1p[1][tid] + b1[0];
        f2g[qb + tid] = f2p[0][tid] + f2p[1][tid] + b2[0];
    }
}

// ---------------- kernel B v5 ----------------
// grid 512, block 256 (4 waves). Block = 16 q-rows, wave h = j-split (64 j
// per round of 256 j), 32 rounds. Single barrier/round; bias via
// global_load_lds double-buffer; fts/f2 direct-to-reg.
__global__ __launch_bounds__(256) void attn_main(
    const float* __restrict__ bias, const unsigned short* __restrict__ ftsT,
    const float* __restrict__ f1g, const float* __restrict__ f2g,
    float* __restrict__ out)
{
    __shared__ float blds[2][16][260];       // 33.3 KB; 1KB DMA chunk + 16B pad
    __shared__ float macc[4][16][68];        // 17.4 KB merge area
    __shared__ float mlm[4][16];
    __shared__ float mll[4][16];

    const int tid = threadIdx.x;
    const int qb = blockIdx.x * 16;
    const int h = tid >> 6;                   // wave = j-split 0..3
    const int lane = tid & 63, c = lane & 15, g = lane >> 4;

    const float f1r = f1g[qb + c];

    float m = -INFINITY, lsum = 0.f;
    f32x4 acc[4] = {};

    // stage 4 rows (1KB each) of round r into blds[buf]
    auto issue_round = [&](int r, int buf) {
        #pragma unroll
        for (int i = 0; i < 4; ++i) {
            const int row = h * 4 + i;
            const float* gsrc = bias + (long)(qb + row) * 8192 + r * 256 + lane * 4;
            gld_lds16(gsrc, &blds[buf][row][0]);
        }
    };

    auto do_ks = [&](int r, int ks) {
        const int jcol = h * 64 + ks * 32 + g * 8;
        const float* bl = &blds[r & 1][c][jcol];
        float4 b0 = *(const float4*)(bl);
        float4 b1v = *(const float4*)(bl + 4);
        const int jg = r * 256 + jcol;
        const unsigned short* fp = ftsT + (long)c * 8192 + jg;
        bf16x8 ff0 = *(const bf16x8*)(fp);
        bf16x8 ff1 = *(const bf16x8*)(fp + 16 * 8192);
        bf16x8 ff2 = *(const bf16x8*)(fp + 32 * 8192);
        bf16x8 ff3 = *(const bf16x8*)(fp + 48 * 8192);
        const float* qp = f2g + jg;
        float4 fa = ((const float4*)qp)[0];
        float4 fb = ((const float4*)qp)[1];

        float bb[8] = { b0.x, b0.y, b0.z, b0.w, b1v.x, b1v.y, b1v.z, b1v.w };
        float f2v[8] = { fa.x, fa.y, fa.z, fa.w, fb.x, fb.y, fb.z, fb.w };
        float s[8];
        float tm = -INFINITY;
        #pragma unroll
        for (int i = 0; i < 8; ++i) {
            float z = f1r + f2v[i];
            z = fmaxf(z, 0.2f * z);               // leaky_relu(0.2)
            float sv = z + bb[i];
            s[i] = sv;
            tm = fmaxf(tm, sv);
        }
        tm = fmaxf(tm, __shfl_xor(tm, 16, 64));
        tm = fmaxf(tm, __shfl_xor(tm, 32, 64));
        if (!__all(tm <= m + 8.f)) {              // defer-max (T13)
            float mnew = fmaxf(m, tm);
            float sc = __expf(m - mnew);
            lsum *= sc;
            float scq0 = __shfl(sc, g * 4 + 0, 64);
            float scq1 = __shfl(sc, g * 4 + 1, 64);
            float scq2 = __shfl(sc, g * 4 + 2, 64);
            float scq3 = __shfl(sc, g * 4 + 3, 64);
            #pragma unroll
            for (int ob = 0; ob < 4; ++ob) {
                acc[ob][0] *= scq0; acc[ob][1] *= scq1;
                acc[ob][2] *= scq2; acc[ob][3] *= scq3;
            }
            m = mnew;
        }
        float ts = 0.f;
        bf16x8 af;
        #pragma unroll
        for (int i = 0; i < 8; ++i) {
            float p = __expf(s[i] - m);           // bounded by e^8 when deferred
            ts += p;
            af[i] = (short)f2bf(p);
        }
        ts += __shfl_xor(ts, 16, 64);
        ts += __shfl_xor(ts, 32, 64);
        lsum += ts;
        acc[0] = __builtin_amdgcn_mfma_f32_16x16x32_bf16(af, ff0, acc[0], 0, 0, 0);
        acc[1] = __builtin_amdgcn_mfma_f32_16x16x32_bf16(af, ff1, acc[1], 0, 0, 0);
        acc[2] = __builtin_amdgcn_mfma_f32_16x16x32_bf16(af, ff2, acc[2], 0, 0, 0);
        acc[3] = __builtin_amdgcn_mfma_f32_16x16x32_bf16(af, ff3, acc[3], 0, 0, 0);
    };

    issue_round(0, 0);
    #pragma unroll 1
    for (int r = 0; r < 32; ++r) {
        __syncthreads();                          // drains round r (issued 1 round ago)
        if (r + 1 < 32) issue_round(r + 1, (r + 1) & 1);
        do_ks(r, 0);
        do_ks(r, 1);
    }

    __syncthreads();
    #pragma unroll
    for (int ob = 0; ob < 4; ++ob) {
        macc[h][g * 4 + 0][ob * 16 + c] = acc[ob][0];
        macc[h][g * 4 + 1][ob * 16 + c] = acc[ob][1];
        macc[h][g * 4 + 2][ob * 16 + c] = acc[ob][2];
        macc[h][g * 4 + 3][ob * 16 + c] = acc[ob][3];
    }
    if (lane < 16) { mlm[h][c] = m; mll[h][c] = lsum; }
    __syncthreads();

    // merge 4 j-splits, normalize, elu, store: 256 thr x 4 outputs
    {
        const int row = tid >> 4;            // 0..15
        const int o0 = (tid & 15) * 4;
        float m0 = mlm[0][row], m1 = mlm[1][row];
        float m2 = mlm[2][row], m3 = mlm[3][row];
        float ms = fmaxf(fmaxf(m0, m1), fmaxf(m2, m3));
        float w0 = __expf(m0 - ms), w1 = __expf(m1 - ms);
        float w2 = __expf(m2 - ms), w3 = __expf(m3 - ms);
        float den = mll[0][row] * w0 + mll[1][row] * w1 +
                    mll[2][row] * w2 + mll[3][row] * w3;
        float inv = 1.f / den;
        float4 v0 = *(const float4*)(&macc[0][row][o0]);
        float4 v1 = *(const float4*)(&macc[1][row][o0]);
        float4 v2 = *(const float4*)(&macc[2][row][o0]);
        float4 v3 = *(const float4*)(&macc[3][row][o0]);
        float4 res;
        res.x = elu1((v0.x * w0 + v1.x * w1 + v2.x * w2 + v3.x * w3) * inv);
        res.y = elu1((v0.y * w0 + v1.y * w1 + v2.y * w2 + v3.y * w3) * inv);
        res.z = elu1((v0.z * w0 + v1.z * w1 + v2.z * w2 + v3.z * w3) * inv);
        res.w = elu1((v0.w * w0 + v1.w * w1 + v2.w * w2 + v3.w * w3) * inv);
        *(float4*)(&out[(long)(qb + row) * 64 + o0]) = res;
    }
}

extern "C" void kernel_launch(void* const* d_in, const int* in_sizes, int n_in,
                              void* d_out, int out_size, void* d_ws, size_t ws_size,
                              hipStream_t stream) {
    (void)in_sizes; (void)n_in; (void)out_size; (void)ws_size;
    const float* seq  = (const float*)d_in[0];
    const float* bias = (const float*)d_in[1];
    const float* W1   = (const float*)d_in[2];
    const float* a1   = (const float*)d_in[3];
    const float* b1   = (const float*)d_in[4];
    const float* a2   = (const float*)d_in[5];
    const float* b2   = (const float*)d_in[6];
    float* out = (float*)d_out;

    unsigned short* ftsT = (unsigned short*)d_ws;                      // 1 MB
    float* f1 = (float*)((char*)d_ws + 64 * 8192 * 2);                 // 32 KB
    float* f2 = (float*)((char*)d_ws + 64 * 8192 * 2 + 8192 * 4);      // 32 KB

    hipLaunchKernelGGL(attn_fts, dim3(256), dim3(256), 0, stream,
                       seq, W1, a1, b1, a2, b2, ftsT, f1, f2);
    hipLaunchKernelGGL(attn_main, dim3(512), dim3(256), 0, stream,
                       bias, ftsT, f1, f2, out);
}

// Round 9
// 387.795 us; speedup vs baseline: 1.1839x; 1.0207x over previous
//
#include <hip/hip_runtime.h>
#include <hip/hip_bf16.h>

// GAT attention head, N=8192, F_IN=256, OUT=64, bias_mat [N,N] f32.
// kA: fts = seq@W1 (bf16 MFMA), f1/f2 rank-1 terms, ftsT bf16 for PV B-frags.
// kB v6: counted-vmcnt deep pipeline (T4). Per round r: wait vmcnt(4) (keeps
//   bias(r+1) DMA in flight - NEVER drain to 0), raw s_barrier, then batch
//   [fts(r+1)->regs, bias(r+2)->gld_lds] in pinned FIFO order, then compute.
//   4 bias LDS buffers; fts regs ping-pong (named scalars, no arrays);
//   merge area aliases bias LDS after the loop. 512 blk x 256 thr, 2 blk/CU.
// (3rd resubmission of round-6 kernel: broker at capacity 3x, no data yet.)

typedef float f32x4 __attribute__((ext_vector_type(4)));
typedef short bf16x8 __attribute__((ext_vector_type(8)));

#define WAITCNT4() asm volatile("s_waitcnt vmcnt(4)" ::: "memory")
#define WAITCNT0() asm volatile("s_waitcnt vmcnt(0)" ::: "memory")
#define SBAR() __builtin_amdgcn_s_barrier()
#define SCHEDB() __builtin_amdgcn_sched_barrier(0)

__device__ __forceinline__ unsigned short f2bf(float x) {
    union { float f; unsigned u; } v; v.f = x;
    unsigned r = v.u + 0x7FFF + ((v.u >> 16) & 1);   // RNE
    return (unsigned short)(r >> 16);
}

__device__ __forceinline__ float elu1(float x) {
    return x > 0.f ? x : (__expf(x) - 1.f);
}

// async global -> LDS, 16B per lane (wave-uniform LDS base, per-lane gsrc)
__device__ __forceinline__ void gld_lds16(const void* g, void* l) {
    __builtin_amdgcn_global_load_lds(
        (const __attribute__((address_space(1))) void*)(unsigned long long)g,
        (__attribute__((address_space(3))) void*)(unsigned)(unsigned long long)l,
        16, 0, 0);
}

// ---------------- kernel A: fts, f1, f2, ftsT ---------------- (r1-verified)
__global__ __launch_bounds__(256) void attn_fts(
    const float* __restrict__ seq, const float* __restrict__ W1,
    const float* __restrict__ a1, const float* __restrict__ b1,
    const float* __restrict__ a2, const float* __restrict__ b2,
    unsigned short* __restrict__ ftsT, float* __restrict__ f1g,
    float* __restrict__ f2g)
{
    __shared__ unsigned short w1t[64 * 264];
    __shared__ unsigned short stage[64 * 40];
    __shared__ float f1p[2][32];
    __shared__ float f2p[2][32];

    const int tid = threadIdx.x;
    const int qb = blockIdx.x * 32;
    const int w = tid >> 6, rg = w & 1, oh = w >> 1;
    const int lane = tid & 63, c = lane & 15, g = lane >> 4;

    for (int i = 0; i < 64; ++i) {
        int e = tid + i * 256;            // e = k*64 + o
        int k = e >> 6, o = e & 63;
        w1t[o * 264 + k] = f2bf(W1[e]);
    }
    __syncthreads();

    f32x4 acc[2] = {};
    const float* srow = seq + (long)(qb + rg * 16 + c) * 256;
    #pragma unroll
    for (int ks = 0; ks < 8; ++ks) {
        int k0 = ks * 32 + g * 8;
        float4 s0 = *(const float4*)(srow + k0);
        float4 s1 = *(const float4*)(srow + k0 + 4);
        bf16x8 af;
        af[0] = (short)f2bf(s0.x); af[1] = (short)f2bf(s0.y);
        af[2] = (short)f2bf(s0.z); af[3] = (short)f2bf(s0.w);
        af[4] = (short)f2bf(s1.x); af[5] = (short)f2bf(s1.y);
        af[6] = (short)f2bf(s1.z); af[7] = (short)f2bf(s1.w);
        #pragma unroll
        for (int ob = 0; ob < 2; ++ob) {
            int brow = oh * 32 + ob * 16 + c;
            bf16x8 bf = *(const bf16x8*)(&w1t[brow * 264 + k0]);
            acc[ob] = __builtin_amdgcn_mfma_f32_16x16x32_bf16(af, bf, acc[ob], 0, 0, 0);
        }
    }

    float a1v0 = a1[oh * 32 + c], a1v1 = a1[oh * 32 + 16 + c];
    float a2v0 = a2[oh * 32 + c], a2v1 = a2[oh * 32 + 16 + c];
    #pragma unroll
    for (int reg = 0; reg < 4; ++reg) {
        float p1 = acc[0][reg] * a1v0 + acc[1][reg] * a1v1;
        float p2 = acc[0][reg] * a2v0 + acc[1][reg] * a2v1;
        #pragma unroll
        for (int mm = 1; mm < 16; mm <<= 1) {
            p1 += __shfl_xor(p1, mm, 64);
            p2 += __shfl_xor(p2, mm, 64);
        }
        if (c == 0) {
            f1p[oh][rg * 16 + g * 4 + reg] = p1;
            f2p[oh][rg * 16 + g * 4 + reg] = p2;
        }
    }

    #pragma unroll
    for (int ob = 0; ob < 2; ++ob) {
        int row = oh * 32 + ob * 16 + c;
        #pragma unroll
        for (int rp = 0; rp < 2; ++rp) {
            unsigned short lo = f2bf(acc[ob][rp * 2]);
            unsigned short hi = f2bf(acc[ob][rp * 2 + 1]);
            unsigned v = (unsigned)lo | ((unsigned)hi << 16);
            *(unsigned*)(&stage[row * 40 + rg * 16 + g * 4 + rp * 2]) = v;
        }
    }
    __syncthreads();

    {
        int o = tid >> 2, q4 = tid & 3;
        uint4 v = *(const uint4*)(&stage[o * 40 + q4 * 8]);
        *(uint4*)(&ftsT[(long)o * 8192 + qb + q4 * 8]) = v;
    }
    if (tid < 32) {
        f1g[qb + tid] = f1p[0][tid] + f1p[1][tid] + b1[0];
        f2g[qb + tid] = f2p[0][tid] + f2p[1][tid] + b2[0];
    }
}

// ---------------- kernel B v6 ----------------
// grid 512, block 256 (4 waves). Block = 16 q-rows, wave h = 64-j split,
// round = 256 j, 32 rounds. Counted-vmcnt pipeline, 4 bias buffers.
__global__ __launch_bounds__(256, 2) void attn_main(
    const float* __restrict__ bias, const unsigned short* __restrict__ ftsT,
    const float* __restrict__ f1g, const float* __restrict__ f2g,
    float* __restrict__ out)
{
    __shared__ float blds[4][16][260];       // 66.6 KB; merge aliases this

    const int tid = threadIdx.x;
    const int qb = blockIdx.x * 16;
    const int h = tid >> 6;                   // wave = j-split 0..3
    const int lane = tid & 63, c = lane & 15, g = lane >> 4;

    const float f1r = f1g[qb + c];

    float m = -INFINITY, lsum = 0.f;
    f32x4 acc[4] = {};

    // ---- bias staging: wave h stages rows h*4..h*4+3 (1KB each) ----
    auto issue_bias = [&](int r) {
        const int buf = r & 3;
        #pragma unroll
        for (int i = 0; i < 4; ++i) {
            const int row = h * 4 + i;
            const float* gsrc = bias + (long)(qb + row) * 8192 + r * 256 + lane * 4;
            gld_lds16(gsrc, &blds[buf][row][0]);
        }
    };

    // ---- fts/f2 register sets (named scalars; ping-pong A/B) ----
    bf16x8 A00, A01, A02, A03, A10, A11, A12, A13;
    float4 Af0, Af1, Af2, Af3;
    bf16x8 B00, B01, B02, B03, B10, B11, B12, B13;
    float4 Bf0, Bf1, Bf2, Bf3;

    auto loadF_A = [&](int r) {
        const unsigned short* p = ftsT + (long)c * 8192 + r * 256 + h * 64 + g * 8;
        A00 = *(const bf16x8*)(p);
        A01 = *(const bf16x8*)(p + 16 * 8192);
        A02 = *(const bf16x8*)(p + 32 * 8192);
        A03 = *(const bf16x8*)(p + 48 * 8192);
        A10 = *(const bf16x8*)(p + 32);
        A11 = *(const bf16x8*)(p + 32 + 16 * 8192);
        A12 = *(const bf16x8*)(p + 32 + 32 * 8192);
        A13 = *(const bf16x8*)(p + 32 + 48 * 8192);
        const float* q = f2g + r * 256 + h * 64 + g * 8;
        Af0 = ((const float4*)q)[0]; Af1 = ((const float4*)q)[1];
        Af2 = ((const float4*)(q + 32))[0]; Af3 = ((const float4*)(q + 32))[1];
    };
    auto loadF_B = [&](int r) {
        const unsigned short* p = ftsT + (long)c * 8192 + r * 256 + h * 64 + g * 8;
        B00 = *(const bf16x8*)(p);
        B01 = *(const bf16x8*)(p + 16 * 8192);
        B02 = *(const bf16x8*)(p + 32 * 8192);
        B03 = *(const bf16x8*)(p + 48 * 8192);
        B10 = *(const bf16x8*)(p + 32);
        B11 = *(const bf16x8*)(p + 32 + 16 * 8192);
        B12 = *(const bf16x8*)(p + 32 + 32 * 8192);
        B13 = *(const bf16x8*)(p + 32 + 48 * 8192);
        const float* q = f2g + r * 256 + h * 64 + g * 8;
        Bf0 = ((const float4*)q)[0]; Bf1 = ((const float4*)q)[1];
        Bf2 = ((const float4*)(q + 32))[0]; Bf3 = ((const float4*)(q + 32))[1];
    };

    auto do_ks = [&](int r, int ks, bf16x8 ff0, bf16x8 ff1, bf16x8 ff2,
                     bf16x8 ff3, float4 fa, float4 fb) {
        const int jcol = h * 64 + ks * 32 + g * 8;
        const float* bl = &blds[r & 3][c][jcol];
        float4 b0 = *(const float4*)(bl);
        float4 b1v = *(const float4*)(bl + 4);
        float bb[8] = { b0.x, b0.y, b0.z, b0.w, b1v.x, b1v.y, b1v.z, b1v.w };
        float f2v[8] = { fa.x, fa.y, fa.z, fa.w, fb.x, fb.y, fb.z, fb.w };
        float s[8];
        float tm = -INFINITY;
        #pragma unroll
        for (int i = 0; i < 8; ++i) {
            float z = f1r + f2v[i];
            z = fmaxf(z, 0.2f * z);               // leaky_relu(0.2)
            float sv = z + bb[i];
            s[i] = sv;
            tm = fmaxf(tm, sv);
        }
        tm = fmaxf(tm, __shfl_xor(tm, 16, 64));
        tm = fmaxf(tm, __shfl_xor(tm, 32, 64));
        if (!__all(tm <= m + 8.f)) {              // defer-max (T13)
            float mnew = fmaxf(m, tm);
            float sc = __expf(m - mnew);
            lsum *= sc;
            float scq0 = __shfl(sc, g * 4 + 0, 64);
            float scq1 = __shfl(sc, g * 4 + 1, 64);
            float scq2 = __shfl(sc, g * 4 + 2, 64);
            float scq3 = __shfl(sc, g * 4 + 3, 64);
            #pragma unroll
            for (int ob = 0; ob < 4; ++ob) {
                acc[ob][0] *= scq0; acc[ob][1] *= scq1;
                acc[ob][2] *= scq2; acc[ob][3] *= scq3;
            }
            m = mnew;
        }
        float ts = 0.f;
        bf16x8 af;
        #pragma unroll
        for (int i = 0; i < 8; ++i) {
            float p = __expf(s[i] - m);           // bounded by e^8 when deferred
            ts += p;
            af[i] = (short)f2bf(p);
        }
        ts += __shfl_xor(ts, 16, 64);
        ts += __shfl_xor(ts, 32, 64);
        lsum += ts;
        acc[0] = __builtin_amdgcn_mfma_f32_16x16x32_bf16(af, ff0, acc[0], 0, 0, 0);
        acc[1] = __builtin_amdgcn_mfma_f32_16x16x32_bf16(af, ff1, acc[1], 0, 0, 0);
        acc[2] = __builtin_amdgcn_mfma_f32_16x16x32_bf16(af, ff2, acc[2], 0, 0, 0);
        acc[3] = __builtin_amdgcn_mfma_f32_16x16x32_bf16(af, ff3, acc[3], 0, 0, 0);
    };

    // prologue: fts(0)->A, bias(0), bias(1)   [FIFO: ftsA(12), b0(4), b1(4)]
    loadF_A(0);
    SCHEDB();
    issue_bias(0);
    issue_bias(1);

    // rounds 0..29 (steady state): wait vmcnt(4) keeps bias(r+1) in flight
    #pragma unroll 1
    for (int rp = 0; rp < 15; ++rp) {
        const int r = 2 * rp;
        WAITCNT4(); SBAR(); SCHEDB();             // bias(r), fts(r) retired
        loadF_B(r + 1);
        SCHEDB();
        issue_bias(r + 2);
        SCHEDB();
        do_ks(r, 0, A00, A01, A02, A03, Af0, Af1);
        do_ks(r, 1, A10, A11, A12, A13, Af2, Af3);

        WAITCNT4(); SBAR(); SCHEDB();
        loadF_A(r + 2);
        SCHEDB();
        issue_bias(r + 3);
        SCHEDB();
        do_ks(r + 1, 0, B00, B01, B02, B03, Bf0, Bf1);
        do_ks(r + 1, 1, B10, B11, B12, B13, Bf2, Bf3);
    }
    // round 30: outstanding = bias30(4)+fts30(12)+bias31(4)
    WAITCNT4(); SBAR(); SCHEDB();
    loadF_B(31);
    SCHEDB();
    do_ks(30, 0, A00, A01, A02, A03, Af0, Af1);
    do_ks(30, 1, A10, A11, A12, A13, Af2, Af3);
    // round 31: outstanding = bias31(4)+fts31(12) -> need all
    WAITCNT0(); SBAR(); SCHEDB();
    do_ks(31, 0, B00, B01, B02, B03, Bf0, Bf1);
    do_ks(31, 1, B10, B11, B12, B13, Bf2, Bf3);

    __syncthreads();                              // all bias reads done
    // merge area aliases blds
    float (*macc)[16][68] = (float (*)[16][68])(&blds[0][0][0]);
    float* mlm = ((float*)macc) + 4 * 16 * 68;
    float* mll = mlm + 64;

    #pragma unroll
    for (int ob = 0; ob < 4; ++ob) {
        macc[h][g * 4 + 0][ob * 16 + c] = acc[ob][0];
        macc[h][g * 4 + 1][ob * 16 + c] = acc[ob][1];
        macc[h][g * 4 + 2][ob * 16 + c] = acc[ob][2];
        macc[h][g * 4 + 3][ob * 16 + c] = acc[ob][3];
    }
    if (lane < 16) { mlm[h * 16 + c] = m; mll[h * 16 + c] = lsum; }
    __syncthreads();

    // merge 4 j-splits, normalize, elu, store: 256 thr x 4 outputs
    {
        const int row = tid >> 4;            // 0..15
        const int o0 = (tid & 15) * 4;
        float m0 = mlm[0 * 16 + row], m1 = mlm[1 * 16 + row];
        float m2 = mlm[2 * 16 + row], m3 = mlm[3 * 16 + row];
        float ms = fmaxf(fmaxf(m0, m1), fmaxf(m2, m3));
        float w0 = __expf(m0 - ms), w1 = __expf(m1 - ms);
        float w2 = __expf(m2 - ms), w3 = __expf(m3 - ms);
        float den = mll[0 * 16 + row] * w0 + mll[1 * 16 + row] * w1 +
                    mll[2 * 16 + row] * w2 + mll[3 * 16 + row] * w3;
        float inv = 1.f / den;
        float4 v0 = *(const float4*)(&macc[0][row][o0]);
        float4 v1 = *(const float4*)(&macc[1][row][o0]);
        float4 v2 = *(const float4*)(&macc[2][row][o0]);
        float4 v3 = *(const float4*)(&macc[3][row][o0]);
        float4 res;
        res.x = elu1((v0.x * w0 + v1.x * w1 + v2.x * w2 + v3.x * w3) * inv);
        res.y = elu1((v0.y * w0 + v1.y * w1 + v2.y * w2 + v3.y * w3) * inv);
        res.z = elu1((v0.z * w0 + v1.z * w1 + v2.z * w2 + v3.z * w3) * inv);
        res.w = elu1((v0.w * w0 + v1.w * w1 + v2.w * w2 + v3.w * w3) * inv);
        *(float4*)(&out[(long)(qb + row) * 64 + o0]) = res;
    }
}

extern "C" void kernel_launch(void* const* d_in, const int* in_sizes, int n_in,
                              void* d_out, int out_size, void* d_ws, size_t ws_size,
                              hipStream_t stream) {
    (void)in_sizes; (void)n_in; (void)out_size; (void)ws_size;
    const float* seq  = (const float*)d_in[0];
    const float* bias = (const float*)d_in[1];
    const float* W1   = (const float*)d_in[2];
    const float* a1   = (const float*)d_in[3];
    const float* b1   = (const float*)d_in[4];
    const float* a2   = (const float*)d_in[5];
    const float* b2   = (const float*)d_in[6];
    float* out = (float*)d_out;

    unsigned short* ftsT = (unsigned short*)d_ws;                      // 1 MB
    float* f1 = (float*)((char*)d_ws + 64 * 8192 * 2);                 // 32 KB
    float* f2 = (float*)((char*)d_ws + 64 * 8192 * 2 + 8192 * 4);      // 32 KB

    hipLaunchKernelGGL(attn_fts, dim3(256), dim3(256), 0, stream,
                       seq, W1, a1, b1, a2, b2, ftsT, f1, f2);
    hipLaunchKernelGGL(attn_main, dim3(512), dim3(256), 0, stream,
                       bias, ftsT, f1, f2, out);
}